// Round 10
// baseline (48.577 us; speedup 1.0000x reference)
//
#include <hip/hip_runtime.h>
#include <hip/hip_bf16.h>

typedef __attribute__((ext_vector_type(2))) _Float16 half2v;
typedef __attribute__((ext_vector_type(8))) _Float16 half8v;
typedef __attribute__((ext_vector_type(4))) float f32x4;

#define NBLK 2048   // multiple of 8 (XCD chunking)

// Fused: out = feat + bias (blocks [0,initB)), Wz f16 pack (blocks [initB, ...))
// Wz column mapping (K-permutation): k = t*32 + gg*8 + j  <->  c = (gg>>1)*8 + t,
// i = (gg&1)*8 + j  (t<8);  t==8: k=256+gg*8+j -> be row gg*8+j (gg<2), 0 pad.
__global__ __launch_bounds__(256) void setup_kernel(
    const float* __restrict__ feat, const float* __restrict__ bias,
    const float* __restrict__ We, const float* __restrict__ be,
    float* __restrict__ out, unsigned short* __restrict__ wp,
    int n_elems, int initB) {
  if ((int)blockIdx.x < initB) {
    int g = blockIdx.x * 256 + threadIdx.x;
    int base = g * 4;
    if (base < n_elems) {
      float4 f = *reinterpret_cast<const float4*>(feat + base);
      const float4* b4 = reinterpret_cast<const float4*>(bias);
      float4 b = b4[g & 3];
      float4 o;
      o.x = f.x + b.x; o.y = f.y + b.y; o.z = f.z + b.z; o.w = f.w + b.w;
      *reinterpret_cast<float4*>(out + base) = o;
    }
  } else {
    int idx = (blockIdx.x - initB) * 256 + threadIdx.x;
    if (idx < 9 * 4 * 16 * 8) {
      int j = idx & 7, n = (idx >> 3) & 15, gg = (idx >> 7) & 3, t = idx >> 9;
      float v = 0.f;
      if (t < 8) {
        int c = (gg >> 1) * 8 + t;
        int i = (gg & 1) * 8 + j;
        v = We[c * 256 + i * 16 + n];
      } else if (gg < 2) {
        v = be[(gg * 8 + j) * 16 + n];
      }
      _Float16 hv = (_Float16)v;
      wp[idx] = __builtin_bit_cast(unsigned short, hv);
    }
  }
}

// DMA one 16-edge tile (1KB) of efeat into this wave's LDS slice.
// LDS dest is wave-uniform base + lane*16 (HW rule). Source is per-lane:
// granule swizzle sigma: LDS granule L holds (edge = L>>2, slot = (L&3)^((L>>3)&3))
// -> tile reads become 4-way bank conflicts instead of 8-way.
__device__ __forceinline__ void stage_tile(const float* __restrict__ efeat,
                                           long tile, long E, int lane,
                                           float* lds_base /*wave-uniform*/) {
  int edge = lane >> 2;
  int slot = (lane & 3) ^ ((lane >> 3) & 3);
  long off = tile * 1024 + (long)edge * 64 + (long)slot * 16;  // bytes
  long mx = E * 64 - 16;
  off = off > mx ? mx : off;   // clamp (generic tail safety; masked at compute)
  __builtin_amdgcn_global_load_lds(
      (const __attribute__((address_space(1))) unsigned int*)((const char*)efeat + off),
      (__attribute__((address_space(3))) unsigned int*)lds_base,
      16, 0, 0);
}

// read granule h (0..3) of edge m from the swizzled tile buffer
__device__ __forceinline__ float4 lds_tile_read(const float* buf, int m, int h) {
  int q = 4 * m + (h ^ ((m >> 1) & 3));
  return *reinterpret_cast<const float4*>(buf + q * 4);
}

// A-frag: edge m=lane&15, K-slice k=g*8+j; Z[k] = ef[(g>>1)*8+t] * h[(g&1)*8+j]
// B-frag Bf[t]: lane reads wp[(t*64+lane)*8]. D: col=m, row=g*4+r.
// ef comes from LDS (staged); H from registers (prefetched gather).
__device__ __forceinline__ void compute_tile(
    const float* __restrict__ ebuf, float4 H0, float4 H1, int4 dd,
    bool hvalid, int g, int m, const half8v* Bf, float* __restrict__ out) {
  int p = g >> 1;
  float4 E0 = lds_tile_read(ebuf, m, 2 * p);
  float4 E1 = lds_tile_read(ebuf, m, 2 * p + 1);
  if (!hvalid) { H0 = make_float4(0.f, 0.f, 0.f, 0.f); H1 = H0; }  // h=0 kills all K-tiles

  half2v ef2[4], h2[4];
  ef2[0] = half2v{(_Float16)E0.x, (_Float16)E0.y};
  ef2[1] = half2v{(_Float16)E0.z, (_Float16)E0.w};
  ef2[2] = half2v{(_Float16)E1.x, (_Float16)E1.y};
  ef2[3] = half2v{(_Float16)E1.z, (_Float16)E1.w};
  h2[0]  = half2v{(_Float16)H0.x, (_Float16)H0.y};
  h2[1]  = half2v{(_Float16)H0.z, (_Float16)H0.w};
  h2[2]  = half2v{(_Float16)H1.x, (_Float16)H1.y};
  h2[3]  = half2v{(_Float16)H1.z, (_Float16)H1.w};

  f32x4 accA = {0.f, 0.f, 0.f, 0.f};
  f32x4 accB = {0.f, 0.f, 0.f, 0.f};
#pragma unroll
  for (int t = 0; t < 8; ++t) {
    _Float16 ev = ef2[t >> 1][t & 1];
    half2v evb = half2v{ev, ev};
    half2v a0 = evb * h2[0], a1 = evb * h2[1], a2 = evb * h2[2], a3 = evb * h2[3];
    half8v A;
    A[0] = a0[0]; A[1] = a0[1]; A[2] = a1[0]; A[3] = a1[1];
    A[4] = a2[0]; A[5] = a2[1]; A[6] = a3[0]; A[7] = a3[1];
    if (t & 1)
      accB = __builtin_amdgcn_mfma_f32_16x16x32_f16(A, Bf[t], accB, 0, 0, 0);
    else
      accA = __builtin_amdgcn_mfma_f32_16x16x32_f16(A, Bf[t], accA, 0, 0, 0);
  }
  {  // be passthrough K-tile (Z = h[i] at k=256+i), zero pad k>=272
    half2v z = half2v{(_Float16)0.f, (_Float16)0.f};
    half2v b0 = (g < 2) ? h2[0] : z, b1 = (g < 2) ? h2[1] : z;
    half2v b2 = (g < 2) ? h2[2] : z, b3 = (g < 2) ? h2[3] : z;
    half8v A;
    A[0] = b0[0]; A[1] = b0[1]; A[2] = b1[0]; A[3] = b1[1];
    A[4] = b2[0]; A[5] = b2[1]; A[6] = b3[0]; A[7] = b3[1];
    accB = __builtin_amdgcn_mfma_f32_16x16x32_f16(A, Bf[8], accB, 0, 0, 0);
  }
  f32x4 acc;
  acc[0] = accA[0] + accB[0]; acc[1] = accA[1] + accB[1];
  acc[2] = accA[2] + accB[2]; acc[3] = accA[3] + accB[3];

  // fast path: whole tile single dst (sorted => endpoints equal). beta(atomics)>=1 always.
  int nA = __shfl(dd.x, 0, 64);
  int nB = __shfl(dd.w, 48, 64);
  if (nA == nB) {
    float v = acc[0] + acc[1] + acc[2] + acc[3];
    v += __shfl_xor(v, 32, 64);
    v += __shfl_xor(v, 16, 64);
    if (g == 0) unsafeAtomicAdd(out + (size_t)nA * 16 + m, v);
    return;
  }
  // general path: per-group run-combine, one atomic per run (last one unconditional)
  float run = acc[0];
  int cur = dd.x;
  if (dd.y == cur) run += acc[1];
  else { unsafeAtomicAdd(out + (size_t)cur * 16 + m, run); cur = dd.y; run = acc[1]; }
  if (dd.z == cur) run += acc[2];
  else { unsafeAtomicAdd(out + (size_t)cur * 16 + m, run); cur = dd.z; run = acc[2]; }
  if (dd.w == cur) run += acc[3];
  else { unsafeAtomicAdd(out + (size_t)cur * 16 + m, run); cur = dd.w; run = acc[3]; }
  unsafeAtomicAdd(out + (size_t)cur * 16 + m, run);
}

// XCD-chunked waves; per-wave DMA double-buffered efeat staging, no __syncthreads.
__global__ __launch_bounds__(256) void edge_mfma_kernel(
    const float* __restrict__ feat, const float* __restrict__ efeat,
    const int* __restrict__ src, const int* __restrict__ dst,
    const unsigned short* __restrict__ wp,
    float* __restrict__ out, int E) {
  __shared__ float sbuf[4][2][256];   // [wave][buf][1KB tile]
  int wid = threadIdx.x >> 6;
  int lane = threadIdx.x & 63;
  int g = lane >> 4;
  int m = lane & 15;
  int hh = g & 1;

  int ntiles = (E + 15) >> 4;
  const bool partialF = (E & 15) != 0;
  const int lastT = ntiles - 1;

  int T8 = (ntiles + 7) >> 3;
  int xcd = blockIdx.x & 7;
  int wic = (blockIdx.x >> 3) * 4 + wid;
  int CW = (gridDim.x >> 3) * 4;
  int cs = xcd * T8;
  int ce = min(cs + T8, ntiles);

  int t = cs + wic;
  if (t >= ce) return;

  half8v Bf[9];
#pragma unroll
  for (int tt = 0; tt < 9; ++tt)
    Bf[tt] = *reinterpret_cast<const half8v*>(wp + (unsigned)(tt * 64 + lane) * 8);

  const float4* f4 = reinterpret_cast<const float4*>(feat);
  const int4*   d4 = reinterpret_cast<const int4*>(dst);

  // ---- prologue: DMA tile t into buf0; register-prefetch H/dd; src for t+CW ----
  stage_tile(efeat, t, E, lane, &sbuf[wid][0][0]);
  int e0 = t * 16 + m;
  bool v_cur = e0 < E;
  int s0 = src[min(e0, E - 1)];
  int4 dd_cur;
  if (__builtin_expect(partialF && t == lastT, 0)) {
    int b = t * 16 + g * 4;
    dd_cur.x = dst[min(b + 0, E - 1)]; dd_cur.y = dst[min(b + 1, E - 1)];
    dd_cur.z = dst[min(b + 2, E - 1)]; dd_cur.w = dst[min(b + 3, E - 1)];
  } else {
    dd_cur = d4[(unsigned)t * 4 + g];
  }
  float4 H0 = f4[(unsigned)s0 * 4 + hh * 2];
  float4 H1 = f4[(unsigned)s0 * 4 + hh * 2 + 1];
  int t1 = t + CW;
  int s1 = (t1 < ce) ? src[min(t1 * 16 + m, E - 1)] : 0;
  asm volatile("s_waitcnt vmcnt(0)" ::: "memory");
  __builtin_amdgcn_sched_barrier(0);

  int buf = 0;
  while (t1 < ce) {
    int t2 = t1 + CW;
    // 1. DMA next tile's efeat (cannot be sunk by the compiler)
    stage_tile(efeat, t1, E, lane, &sbuf[wid][buf ^ 1][0]);
    // 2. register prefetch: H(t1) via s1 (loaded last iter), dd(t1), src(t2)
    float4 H0n = f4[(unsigned)s1 * 4 + hh * 2];
    float4 H1n = f4[(unsigned)s1 * 4 + hh * 2 + 1];
    int4 dd_n;
    if (__builtin_expect(partialF && t1 == lastT, 0)) {
      int b = t1 * 16 + g * 4;
      dd_n.x = dst[min(b + 0, E - 1)]; dd_n.y = dst[min(b + 1, E - 1)];
      dd_n.z = dst[min(b + 2, E - 1)]; dd_n.w = dst[min(b + 3, E - 1)];
    } else {
      dd_n = d4[(unsigned)t1 * 4 + g];
    }
    int s2 = src[min(t2 * 16 + m, E - 1)];   // clamped; unused if loop exits
    bool v_n = (t1 * 16 + m) < E;
    __builtin_amdgcn_sched_barrier(0);  // pin all issues before compute
    // 3. compute current tile from LDS buf (DMA'd last iter, waited last iter)
    compute_tile(&sbuf[wid][buf][0], H0, H1, dd_cur, v_cur, g, m, Bf, out);
    // 4. counted drain: ops after DMA(t1) = 4 prefetch + beta(>=1) atomics;
    //    vmcnt(5) retires the oldest beta ops incl. the DMA. Never 0 in-loop.
    asm volatile("s_waitcnt vmcnt(5)" ::: "memory");
    __builtin_amdgcn_sched_barrier(0);
    H0 = H0n; H1 = H1n; dd_cur = dd_n; s1 = s2; v_cur = v_n;
    t = t1; t1 = t2; buf ^= 1;
  }
  compute_tile(&sbuf[wid][buf][0], H0, H1, dd_cur, v_cur, g, m, Bf, out);
}

extern "C" void kernel_launch(void* const* d_in, const int* in_sizes, int n_in,
                              void* d_out, int out_size, void* d_ws, size_t ws_size,
                              hipStream_t stream) {
  const float* feat  = (const float*)d_in[0];
  const float* efeat = (const float*)d_in[1];
  const float* We    = (const float*)d_in[2];
  const float* be    = (const float*)d_in[3];
  const float* bias  = (const float*)d_in[4];
  const int*   src   = (const int*)d_in[5];
  const int*   dst   = (const int*)d_in[6];
  float* out = (float*)d_out;

  int E = in_sizes[5];
  int n_elems = out_size;  // 50000*16

  int groups = (n_elems + 3) / 4;
  int initB = (groups + 255) / 256;
  int prepB = (9 * 4 * 16 * 8 + 255) / 256;
  setup_kernel<<<initB + prepB, 256, 0, stream>>>(feat, bias, We, be, out,
                                                  (unsigned short*)d_ws, n_elems, initB);

  edge_mfma_kernel<<<NBLK, 256, 0, stream>>>(feat, efeat, src, dst,
                                             (const unsigned short*)d_ws, out, E);
}

// Round 11
// 43.696 us; speedup vs baseline: 1.1117x; 1.1117x over previous
//
#include <hip/hip_runtime.h>

typedef __attribute__((ext_vector_type(2))) _Float16 half2v;
typedef __attribute__((ext_vector_type(8))) _Float16 half8v;
typedef __attribute__((ext_vector_type(4))) float f32x4;

#define NBLK 2048
#define WT (NBLK * 4)            // total waves in phase A
#define WP_ELEMS (9 * 4 * 16 * 8)
#define RP_OFF 16384             // row_ptr byte offset in d_ws
#define MS_OFF (16384 + 262144)  // m-buffer byte offset in d_ws

// Setup: (a) Wz f16 pack, (b) row_ptr[n] = lower_bound(dst, n), n in [0, N].
// Wz column mapping: k = t*32 + gg*8 + j  <->  c = (gg>>1)*8 + t, i = (gg&1)*8 + j
// (t<8); t==8: be row gg*8+j (gg<2), 0 pad.
__global__ __launch_bounds__(256) void setup_kernel(
    const float* __restrict__ We, const float* __restrict__ be,
    const int* __restrict__ dst,
    unsigned short* __restrict__ wp, int* __restrict__ rp,
    int E, int N) {
  int idx = blockIdx.x * 256 + threadIdx.x;
  if (idx < WP_ELEMS) {
    int j = idx & 7, n = (idx >> 3) & 15, gg = (idx >> 7) & 3, t = idx >> 9;
    float v = 0.f;
    if (t < 8) {
      int c = (gg >> 1) * 8 + t;
      int i = (gg & 1) * 8 + j;
      v = We[c * 256 + i * 16 + n];
    } else if (gg < 2) {
      v = be[(gg * 8 + j) * 16 + n];
    }
    _Float16 hv = (_Float16)v;
    wp[idx] = __builtin_bit_cast(unsigned short, hv);
  }
  if (idx <= N) {
    int lo = 0, hi = E;
    while (lo < hi) {
      int mid = (lo + hi) >> 1;
      if (dst[mid] < idx) lo = mid + 1; else hi = mid;
    }
    rp[idx] = lo;
  }
}

// Phase A per-tile: Z-GEMM via 9x mfma_f32_16x16x32_f16, store D-fragment as f16.
// A-frag: edge m=lane&15, K-slice k=g*8+j; Z[k] = ef[(g>>1)*8+t] * h[(g&1)*8+j].
// D: row(edge) = g*4+r, col(feature) = m. Store ms[tile*256 + lane*4 + r] -> one 8B store.
__device__ __forceinline__ void compute_store(
    unsigned short* __restrict__ ms, int tile,
    float4 E0, float4 E1, float4 H0, float4 H1, bool valid,
    int g, int lane, const half8v* Bf) {
  if (!valid) {
    E0 = make_float4(0.f, 0.f, 0.f, 0.f); E1 = E0; H0 = E0; H1 = E0;
  }
  half2v ef2[4], h2[4];
  ef2[0] = half2v{(_Float16)E0.x, (_Float16)E0.y};
  ef2[1] = half2v{(_Float16)E0.z, (_Float16)E0.w};
  ef2[2] = half2v{(_Float16)E1.x, (_Float16)E1.y};
  ef2[3] = half2v{(_Float16)E1.z, (_Float16)E1.w};
  h2[0]  = half2v{(_Float16)H0.x, (_Float16)H0.y};
  h2[1]  = half2v{(_Float16)H0.z, (_Float16)H0.w};
  h2[2]  = half2v{(_Float16)H1.x, (_Float16)H1.y};
  h2[3]  = half2v{(_Float16)H1.z, (_Float16)H1.w};

  f32x4 accA = {0.f, 0.f, 0.f, 0.f};
  f32x4 accB = {0.f, 0.f, 0.f, 0.f};
#pragma unroll
  for (int t = 0; t < 8; ++t) {
    _Float16 ev = ef2[t >> 1][t & 1];
    half2v evb = half2v{ev, ev};
    half2v a0 = evb * h2[0], a1 = evb * h2[1], a2 = evb * h2[2], a3 = evb * h2[3];
    half8v A;
    A[0] = a0[0]; A[1] = a0[1]; A[2] = a1[0]; A[3] = a1[1];
    A[4] = a2[0]; A[5] = a2[1]; A[6] = a3[0]; A[7] = a3[1];
    if (t & 1)
      accB = __builtin_amdgcn_mfma_f32_16x16x32_f16(A, Bf[t], accB, 0, 0, 0);
    else
      accA = __builtin_amdgcn_mfma_f32_16x16x32_f16(A, Bf[t], accA, 0, 0, 0);
  }
  {  // be passthrough K-tile (Z = h[i] at k=256+i), zero pad k>=272
    half2v z = half2v{(_Float16)0.f, (_Float16)0.f};
    half2v b0 = (g < 2) ? h2[0] : z, b1 = (g < 2) ? h2[1] : z;
    half2v b2 = (g < 2) ? h2[2] : z, b3 = (g < 2) ? h2[3] : z;
    half8v A;
    A[0] = b0[0]; A[1] = b0[1]; A[2] = b1[0]; A[3] = b1[1];
    A[4] = b2[0]; A[5] = b2[1]; A[6] = b3[0]; A[7] = b3[1];
    accB = __builtin_amdgcn_mfma_f32_16x16x32_f16(A, Bf[8], accB, 0, 0, 0);
  }
  half2v lo = half2v{(_Float16)(accA[0] + accB[0]), (_Float16)(accA[1] + accB[1])};
  half2v hi = half2v{(_Float16)(accA[2] + accB[2]), (_Float16)(accA[3] + accB[3])};
  uint2 w;
  w.x = __builtin_bit_cast(unsigned, lo);
  w.y = __builtin_bit_cast(unsigned, hi);
  *reinterpret_cast<uint2*>(ms + (size_t)tile * 256 + lane * 4) = w;
}

// Phase A: persistent waves, 1-ahead payload prefetch, 2-ahead src. No dst, no atomics.
__global__ __launch_bounds__(256) void edge_gemm_kernel(
    const float* __restrict__ feat, const float* __restrict__ efeat,
    const int* __restrict__ src, const unsigned short* __restrict__ wp,
    unsigned short* __restrict__ ms, int E) {
  int wave = blockIdx.x * 4 + (threadIdx.x >> 6);
  int lane = threadIdx.x & 63;
  int g = lane >> 4, m = lane & 15;
  int p = g >> 1, hh = g & 1;

  int ntiles = (E + 15) >> 4;
  if (wave >= ntiles) return;

  half8v Bf[9];
#pragma unroll
  for (int t = 0; t < 9; ++t)
    Bf[t] = *reinterpret_cast<const half8v*>(wp + (unsigned)(t * 64 + lane) * 8);

  const float4* ef4 = reinterpret_cast<const float4*>(efeat);
  const float4* f4  = reinterpret_cast<const float4*>(feat);

  // prologue
  int tile = wave;
  int e0 = tile * 16 + m;
  bool v_cur = e0 < E;
  int ec0 = min(e0, E - 1);
  float4 E0 = ef4[(unsigned)ec0 * 4 + p * 2];
  float4 E1 = ef4[(unsigned)ec0 * 4 + p * 2 + 1];
  int s0 = src[ec0];
  float4 H0 = f4[(unsigned)s0 * 4 + hh * 2];
  float4 H1 = f4[(unsigned)s0 * 4 + hh * 2 + 1];
  int tile1 = tile + WT;
  int s1 = (tile1 < ntiles) ? src[min(tile1 * 16 + m, E - 1)] : 0;

  while (tile1 < ntiles) {
    int tile2 = tile1 + WT;
    int e1 = tile1 * 16 + m;
    int ec1 = min(e1, E - 1);
    float4 E0n = ef4[(unsigned)ec1 * 4 + p * 2];
    float4 E1n = ef4[(unsigned)ec1 * 4 + p * 2 + 1];
    float4 H0n = f4[(unsigned)s1 * 4 + hh * 2];   // s1 loaded last iteration
    float4 H1n = f4[(unsigned)s1 * 4 + hh * 2 + 1];
    int s2 = src[min(tile2 * 16 + m, E - 1)];
    bool v_n = e1 < E;
    __builtin_amdgcn_sched_barrier(0);  // issue all prefetch before compute

    compute_store(ms, tile, E0, E1, H0, H1, v_cur, g, lane, Bf);

    E0 = E0n; E1 = E1n; H0 = H0n; H1 = H1n; s1 = s2; v_cur = v_n;
    tile = tile1; tile1 = tile2;
  }
  compute_store(ms, tile, E0, E1, H0, H1, v_cur, g, lane, Bf);
}

// fragment-layout index of m[e][c] (ushorts): (e>>4)*256 + ((e>>2)&3)*64 + c*4 + (e&3)
__device__ __forceinline__ float ms_at(const unsigned short* ms, int e, int c) {
  unsigned short u = ms[((e >> 4) << 8) + (((e >> 2) & 3) << 6) + (c << 2) + (e & 3)];
  return (float)__builtin_bit_cast(_Float16, u);
}

// Phase B: one 16-lane group per node; walk edge run, vectorized 4-edge (8B) loads.
__global__ __launch_bounds__(256) void segsum_kernel(
    const float* __restrict__ feat, const float* __restrict__ bias,
    const unsigned short* __restrict__ ms, const int* __restrict__ rp,
    float* __restrict__ out, int N) {
  int n = blockIdx.x * 16 + (threadIdx.x >> 4);
  int c = threadIdx.x & 15;
  if (n >= N) return;
  int lo = rp[n], hi = rp[n + 1];
  float sum = 0.f;
  int e = lo;
  while (e < hi && (e & 3)) { sum += ms_at(ms, e, c); ++e; }
  while (e + 4 <= hi) {
    const uint2 v = *reinterpret_cast<const uint2*>(
        ms + ((e >> 4) << 8) + (((e >> 2) & 3) << 6) + (c << 2));
    half2v x = __builtin_bit_cast(half2v, v.x);
    half2v y = __builtin_bit_cast(half2v, v.y);
    sum += (float)x[0] + (float)x[1] + (float)y[0] + (float)y[1];
    e += 4;
  }
  while (e < hi) { sum += ms_at(ms, e, c); ++e; }
  out[n * 16 + c] = sum + feat[n * 16 + c] + bias[c];
}

extern "C" void kernel_launch(void* const* d_in, const int* in_sizes, int n_in,
                              void* d_out, int out_size, void* d_ws, size_t ws_size,
                              hipStream_t stream) {
  const float* feat  = (const float*)d_in[0];
  const float* efeat = (const float*)d_in[1];
  const float* We    = (const float*)d_in[2];
  const float* be    = (const float*)d_in[3];
  const float* bias  = (const float*)d_in[4];
  const int*   src   = (const int*)d_in[5];
  const int*   dst   = (const int*)d_in[6];
  float* out = (float*)d_out;

  int E = in_sizes[5];
  int N = out_size / 16;

  unsigned short* wp = (unsigned short*)d_ws;
  int* rp = (int*)((char*)d_ws + RP_OFF);
  unsigned short* ms = (unsigned short*)((char*)d_ws + MS_OFF);

  int setup_items = (N + 1) > WP_ELEMS ? (N + 1) : WP_ELEMS;
  setup_kernel<<<(setup_items + 255) / 256, 256, 0, stream>>>(We, be, dst, wp, rp, E, N);

  int ntiles = (E + 15) / 16;
  int blocksA = min(NBLK, (ntiles + 3) / 4);
  edge_gemm_kernel<<<blocksA, 256, 0, stream>>>(feat, efeat, src, wp, ms, E);

  int blocksB = (N + 15) / 16;
  segsum_kernel<<<blocksB, 256, 0, stream>>>(feat, bias, ms, rp, out, N);
}